// Round 12
// baseline (383.499 us; speedup 1.0000x reference)
//
#include <hip/hip_runtime.h>

#define NVOC 32000
#define NV4  (NVOC / 4)   // 8000
#define MASKID 31999
#define NBINS2 2048
#define NTHR 512
#define NWAVES (NTHR / 64)
#define LISTCAP 2048

// gumbel band: |g| <= g0 = 0.01  <=>  u in [0.3642006, 0.3715585]; widened f32 edges
#define ULO_F 0.36419f
#define UHI_F 0.37157f
#define INV_G0 100.0

typedef unsigned int u32;
typedef unsigned long long u64;

// e in [0,1] -> fixed-point mass at 2^-32 (f32 arithmetic, monotone in e)
__device__ __forceinline__ u32 fix32(float e) {
    float x = e * 4294967296.0f;
    x = fminf(x, 4294967040.0f);
    return (u32)x;
}

// linear z-bins: b = floor((z+16)*64), clamped to [0, 2047]. t = (z+16)*64.
__device__ __forceinline__ int zbin(float t) {
    int b = (int)floorf(t);
    b = b < 0 ? 0 : b;
    return b > (NBINS2 - 1) ? (NBINS2 - 1) : b;
}
// el = exp(z - top_b) in (e^{-1/64}, 1] for in-range z (0 for far-underflow)
__device__ __forceinline__ float elq(float t, int b) {
    return __expf((t - (float)(b + 1)) * 0.015625f);
}

__global__ __launch_bounds__(NTHR, 8) void mdlm_kernel(
    const int* __restrict__ xin,
    const float* __restrict__ logits,
    const float* __restrict__ tin,
    const float* __restrict__ uin,
    float* __restrict__ out,
    int rows)
{
    __shared__ u64 sHist[NBINS2];       // 16 KB; reused as double sD[] after P1
    __shared__ float sTab[NBINS2];      // 8 KB
    __shared__ u32 sList[LISTCAP];      // 8 KB: P2 = in-bin masses; P3 = band indices
    __shared__ double sRedD[NWAVES];
    __shared__ int sRedI[NWAVES];
    __shared__ float sRedF[NWAVES];
    __shared__ float sTT, sQmaxF;
    __shared__ int sCnt, sCntB, sB, sCross, sMaxDrop, sBref, sNeed, sOvf;
    __shared__ u32 sTau;
    __shared__ u64 sPart;
    __shared__ double sAsD, sSfpD, sScaleB;

    double* sD = (double*)sHist;

    const int row = blockIdx.x;
    if (row >= rows) return;
    const int tid = threadIdx.x;
    const float4* lrow4 = (const float4*)(logits + (size_t)row * NVOC);
    const float4* urow4 = (const float4*)(uin + (size_t)row * NVOC);
    const float* urowf = (const float*)urow4;
    float* prow = out + (size_t)rows + (size_t)row * NVOC;

#pragma unroll
    for (int k = 0; k < 4; ++k) sHist[tid + k * NTHR] = 0ULL;
    if (tid == 0) {
        sCnt = 0; sCntB = 0; sB = -1; sCross = 0; sMaxDrop = -1; sBref = -1;
        sTau = 0xFFFFFFFFu; sPart = 0ULL; sNeed = 0; sOvf = 0;
        sTT = tin[0];
    }
    __syncthreads();

    // ---- P1: bin on raw z, per-bin-normalized mass histogram ----
    for (int v4 = tid; v4 < NV4; v4 += NTHR) {
        float4 f = lrow4[v4];
        if (v4 == (MASKID >> 2)) f.w = -1000000.0f;   // MASKID % 4 == 3
        float zz[4] = {f.x, f.y, f.z, f.w};
#pragma unroll
        for (int e4 = 0; e4 < 4; ++e4) {
            float t = fmaf(zz[e4], 64.0f, 1024.0f);
            int b = zbin(t);
            u32 m = fix32(elq(t, b));
            atomicAdd(&sHist[b], (u64)m);
        }
    }
    __syncthreads();

    // ---- b_ref = highest non-empty bin ----
#pragma unroll
    for (int k = 0; k < 4; ++k) {
        int s = tid + k * NTHR;
        if (sHist[s] != 0ULL) atomicMax(&sBref, s);
    }
    __syncthreads();
    const int bref = sBref;

    // ---- convert to f64 scaled values in place + build sTab ----
#pragma unroll
    for (int k = 0; k < 4; ++k) {
        int s = tid + k * NTHR;
        double sc = exp((double)(s - bref) * 0.015625);
        sTab[s] = (float)sc;
        u64 H = sHist[s];
        sD[s] = (double)H * sc;
    }
    __syncthreads();

    // ---- f64 inclusive suffix scan over 2048 bins ----
    for (int dlt = 1; dlt < NBINS2; dlt <<= 1) {
        double a0 = (tid + dlt < NBINS2) ? sD[tid + dlt] : 0.0;
        double a1 = (tid + NTHR + dlt < NBINS2) ? sD[tid + NTHR + dlt] : 0.0;
        double a2 = (tid + 2 * NTHR + dlt < NBINS2) ? sD[tid + 2 * NTHR + dlt] : 0.0;
        double a3 = (tid + 3 * NTHR + dlt < NBINS2) ? sD[tid + 3 * NTHR + dlt] : 0.0;
        __syncthreads();
        sD[tid] += a0;
        sD[tid + NTHR] += a1;
        sD[tid + 2 * NTHR] += a2;
        sD[tid + 3 * NTHR] += a3;
        __syncthreads();
    }
    const double T = 0.9 * sD[0];

    // ---- crossing detection ----
#pragma unroll
    for (int k = 0; k < 4; ++k) {
        int s = tid + k * NTHR;
        double Ai = sD[s];
        double As = (s + 1 < NBINS2) ? sD[s + 1] : 0.0;
        bool dropped = (As >= T);
        bool keptf = (Ai <= T);
        if (dropped) atomicMax(&sMaxDrop, s);
        if (!dropped && !keptf) { sB = s; sCross = 1; }
    }
    __syncthreads();
    if (tid == 0) {
        int B = sCross ? sB : sMaxDrop;
        sB = B;
        double As = (B + 1 < NBINS2) ? sD[B + 1] : 0.0;
        if (B < 0) As = sD[0];
        sAsD = As;
        sSfpD = As;
        sScaleB = (B >= 0) ? exp((double)(B - bref) * 0.015625) : 1.0;
    }
    __syncthreads();

    const int Bst = sB;
    const int cross = sCross;
    const double AsD = sAsD;
    const double dScaleB = sScaleB;

    // ---- P2: exact in-bin resolution (bin-local integer masses) ----
    if (cross) {
        for (int v4 = tid; v4 < NV4; v4 += NTHR) {
            float4 f = lrow4[v4];
            if (v4 == (MASKID >> 2)) f.w = -1000000.0f;
            float zz[4] = {f.x, f.y, f.z, f.w};
#pragma unroll
            for (int e4 = 0; e4 < 4; ++e4) {
                float t = fmaf(zz[e4], 64.0f, 1024.0f);
                int b = zbin(t);
                if (b == Bst) {
                    u32 m = fix32(elq(t, b));
                    int pos = atomicAdd(&sCnt, 1);
                    if (pos < LISTCAP) sList[pos] = m;
                }
            }
        }
        __syncthreads();
        const int K = sCnt < LISTCAP ? sCnt : LISTCAP;
        for (int jj = tid; jj < K; jj += NTHR) {
            u32 mj = sList[jj];
            u64 isum = 0ULL;
            for (int q2 = 0; q2 < K; ++q2) {
                u32 mv = sList[q2];
                if (mv >= mj) isum += (u64)mv;
            }
            double s = AsD + (double)isum * dScaleB;
            if (s <= T) atomicMin(&sTau, mj);
        }
        __syncthreads();
        u32 tl = sTau;
        if (tl != 0xFFFFFFFFu) {
            u64 part = 0ULL;
            for (int q2 = tid; q2 < K; q2 += NTHR) {
                u32 mv = sList[q2];
                if (mv >= tl) part += (u64)mv;
            }
            if (part) atomicAdd(&sPart, part);
        }
        __syncthreads();
        if (tid == 0 && tl != 0xFFFFFFFFu)
            sSfpD = AsD + (double)sPart * dScaleB;
        __syncthreads();
    }

    const u32 tauU = (cross && sTau != 0xFFFFFFFFu) ? sTau : 0xFFFFFFFFu;
    const float invSf = (float)(4294967296.0 / sSfpD);

    // rescale sTab by invS so P3's p is a single multiply
#pragma unroll
    for (int k = 0; k < 4; ++k) sTab[tid + k * NTHR] *= invSf;

    // mask_prob in f64, replicating the reference expression order
    double mpd, omd;
    {
        double td = (double)sTT;
        mpd = ((1.0 - 1e-3) * (td - 0.05)) / ((1.0 - 1e-3) * td);
        omd = 1.0 - mpd;
    }
    __syncthreads();

    // ---- P3: write p_x0; row-max p; collect gumbel-band hits in REGISTERS ----
    // (no LDS writes in this loop: ds_reads of sTab pipeline freely)
    float maxp = 0.0f;
    u64 pack = 0ULL;    // up to 4 packed u16 indices
    int hcnt = 0;
    for (int v4 = tid; v4 < NV4; v4 += NTHR) {
        float4 uf = urow4[v4];
        float4 f = lrow4[v4];
        if (v4 == (MASKID >> 2)) f.w = -1000000.0f;
        float zz[4] = {f.x, f.y, f.z, f.w};
        float uu[4] = {uf.x, uf.y, uf.z, uf.w};
        float pp[4];
        const int i0 = v4 * 4;
#pragma unroll
        for (int e4 = 0; e4 < 4; ++e4) {
            float t = fmaf(zz[e4], 64.0f, 1024.0f);
            int b = zbin(t);
            float el = elq(t, b);
            bool kept = (b > Bst) || (b == Bst && fix32(el) >= tauU);
            float p = kept ? el * sTab[b] : 0.0f;
            pp[e4] = p;
            maxp = fmaxf(maxp, p);
            bool hit = (uu[e4] >= ULO_F) && (uu[e4] <= UHI_F);
            pack = hit ? ((pack << 16) | (u32)(i0 + e4)) : pack;   // branchless
            hcnt += hit ? 1 : 0;
        }
        float4 po;
        po.x = pp[0]; po.y = pp[1]; po.z = pp[2]; po.w = pp[3];
        ((float4*)prow)[v4] = po;
    }
    // append register-collected hits to sList (off the hot loop)
    if (hcnt > 0) {
        int c = hcnt > 4 ? 4 : hcnt;
        int base = atomicAdd(&sCntB, c);
        for (int j = 0; j < c; ++j) {
            int pos = base + j;
            if (pos < LISTCAP) sList[pos] = (u32)(pack & 0xFFFFu);
            pack >>= 16;
        }
        if (hcnt > 4) sOvf = 1;     // forces certified fallback
    }
    __syncthreads();   // p fully written; band list complete

    // ---- row-max p reduce ----
    for (int off = 32; off > 0; off >>= 1)
        maxp = fmaxf(maxp, __shfl_down(maxp, off, 64));
    if ((tid & 63) == 0) sRedF[tid >> 6] = maxp;
    __syncthreads();
    if (tid == 0) {
        float m = sRedF[0];
        for (int w = 1; w < NWAVES; ++w) m = fmaxf(m, sRedF[w]);
        sQmaxF = m;
    }

    // ---- exact f64 evaluation of band candidates (+ mask candidate) ----
    double best = -1.0e300; int bidx = NVOC;
    {
        const int K = sCntB < LISTCAP ? sCntB : LISTCAP;
        for (int jj = tid; jj < K; jj += NTHR) {
            int i = (int)sList[jj];
            float up = urowf[i];
            float pf = prow[i];
            double q = (double)pf * omd;
            double g = -log(-log((double)up + 1e-10) + 1e-10);
            double r = q / (g + 1e-10);
            if (r > best || (r == best && i < bidx)) { best = r; bidx = i; }
        }
        if (tid == 0) {
            float um = urowf[MASKID];
            double gm = -log(-log((double)um + 1e-10) + 1e-10);
            double rm = mpd / (gm + 1e-10);
            if (rm > best || (rm == best && MASKID < bidx)) { best = rm; bidx = MASKID; }
        }
    }
    for (int off = 32; off > 0; off >>= 1) {
        double ov = __shfl_down(best, off, 64);
        int oi = __shfl_down(bidx, off, 64);
        if (ov > best || (ov == best && oi < bidx)) { best = ov; bidx = oi; }
    }
    if ((tid & 63) == 0) { sRedD[tid >> 6] = best; sRedI[tid >> 6] = bidx; }
    __syncthreads();
    if (tid == 0) {
        best = sRedD[0]; bidx = sRedI[0];
        for (int w = 1; w < NWAVES; ++w) {
            double ov = sRedD[w]; int oi = sRedI[w];
            if (ov > best || (ov == best && oi < bidx)) { best = ov; bidx = oi; }
        }
        // certified bound: any token outside the band has r < qmax*om/g0 (or r <= 0)
        double bound = (double)sQmaxF * omd * INV_G0;
        int need = sOvf || (sCntB > LISTCAP) || !(best > bound);
        sNeed = need;
        if (!need) {
            int xv = xin[row];
            out[row] = (float)((xv == MASKID) ? bidx : xv);
        }
    }
    __syncthreads();

    // ---- fallback: exact f64 argmax over the whole row (provably correct) ----
    if (sNeed) {
        double fb = -1.0e300; int fi = NVOC;
        for (int v4 = tid; v4 < NV4; v4 += NTHR) {
            float4 uf = urow4[v4];
            float4 pf4 = ((const float4*)prow)[v4];
            float uu[4] = {uf.x, uf.y, uf.z, uf.w};
            float pp[4] = {pf4.x, pf4.y, pf4.z, pf4.w};
            const int i0 = v4 * 4;
#pragma unroll
            for (int e4 = 0; e4 < 4; ++e4) {
                const int i = i0 + e4;
                double q = (i == MASKID) ? mpd : (double)pp[e4] * omd;
                double g = -log(-log((double)uu[e4] + 1e-10) + 1e-10);
                double r = q / (g + 1e-10);
                if (r > fb || (r == fb && i < fi)) { fb = r; fi = i; }
            }
        }
        for (int off = 32; off > 0; off >>= 1) {
            double ov = __shfl_down(fb, off, 64);
            int oi = __shfl_down(fi, off, 64);
            if (ov > fb || (ov == fb && oi < fi)) { fb = ov; fi = oi; }
        }
        if ((tid & 63) == 0) { sRedD[tid >> 6] = fb; sRedI[tid >> 6] = fi; }
        __syncthreads();
        if (tid == 0) {
            fb = sRedD[0]; fi = sRedI[0];
            for (int w = 1; w < NWAVES; ++w) {
                double ov = sRedD[w]; int oi = sRedI[w];
                if (ov > fb || (ov == fb && oi < fi)) { fb = ov; fi = oi; }
            }
            int xv = xin[row];
            out[row] = (float)((xv == MASKID) ? fi : xv);
        }
    }
}

extern "C" void kernel_launch(void* const* d_in, const int* in_sizes, int n_in,
                              void* d_out, int out_size, void* d_ws, size_t ws_size,
                              hipStream_t stream) {
    const int* x = (const int*)d_in[0];
    const float* logits = (const float*)d_in[1];
    const float* t = (const float*)d_in[2];
    const float* u = (const float*)d_in[3];
    float* out = (float*)d_out;
    const int rows = in_sizes[0];  // B*S = 2048
    hipLaunchKernelGGL(mdlm_kernel, dim3(rows), dim3(NTHR), 0, stream,
                       x, logits, t, u, out, rows);
}

// Round 13
// 252.427 us; speedup vs baseline: 1.5192x; 1.5192x over previous
//
#include <hip/hip_runtime.h>

#define NVOC 32000
#define NV4  (NVOC / 4)   // 8000
#define MASKID 31999
#define NBINS2 2048
#define NTHR 512
#define NWAVES (NTHR / 64)
#define LISTCAP 2048

typedef unsigned int u32;
typedef unsigned long long u64;

// e in [0,1] -> fixed-point mass at 2^-32 (f32 arithmetic, monotone in e)
__device__ __forceinline__ u32 fix32(float e) {
    float x = e * 4294967296.0f;
    x = fminf(x, 4294967040.0f);
    return (u32)x;
}

// linear z-bins: b = floor((z+16)*64), clamped to [0, 2047]. t = (z+16)*64.
__device__ __forceinline__ int zbin(float t) {
    int b = (int)floorf(t);
    b = b < 0 ? 0 : b;
    return b > (NBINS2 - 1) ? (NBINS2 - 1) : b;
}
// el = exp(z - top_b) in (e^{-1/64}, 1] for in-range z (0 for far-underflow)
__device__ __forceinline__ float elq(float t, int b) {
    return __expf((t - (float)(b + 1)) * 0.015625f);
}

__global__ __launch_bounds__(NTHR, 8) void mdlm_kernel(
    const int* __restrict__ xin,
    const float* __restrict__ logits,
    const float* __restrict__ tin,
    const float* __restrict__ uin,
    float* __restrict__ out,
    int rows)
{
    __shared__ u64 sHist[NBINS2];       // 16 KB; reused as double sD[] after P1
    __shared__ float sTab[NBINS2];      // 8 KB
    __shared__ u32 sList[LISTCAP];      // 8 KB
    __shared__ double sRedD[NWAVES];
    __shared__ int sRedI[NWAVES];
    __shared__ float sTT;
    __shared__ int sCnt, sB, sCross, sMaxDrop, sBref;
    __shared__ u32 sTau;
    __shared__ u64 sPart;
    __shared__ double sAsD, sSfpD, sScaleB;

    double* sD = (double*)sHist;

    const int row = blockIdx.x;
    if (row >= rows) return;
    const int tid = threadIdx.x;
    const int lane = tid & 63;
    const float4* lrow4 = (const float4*)(logits + (size_t)row * NVOC);
    const float4* urow4 = (const float4*)(uin + (size_t)row * NVOC);
    const float* urowf = (const float*)urow4;
    float* prow = out + (size_t)rows + (size_t)row * NVOC;

#pragma unroll
    for (int k = 0; k < 4; ++k) sHist[tid + k * NTHR] = 0ULL;
    if (tid == 0) {
        sCnt = 0; sB = -1; sCross = 0; sMaxDrop = -1; sBref = -1;
        sTau = 0xFFFFFFFFu; sPart = 0ULL;
        sTT = tin[0];
    }
    __syncthreads();

    // ---- P1: bin on raw z, per-bin-normalized mass histogram ----
    for (int v4 = tid; v4 < NV4; v4 += NTHR) {
        float4 f = lrow4[v4];
        if (v4 == (MASKID >> 2)) f.w = -1000000.0f;   // MASKID % 4 == 3
        float zz[4] = {f.x, f.y, f.z, f.w};
#pragma unroll
        for (int e4 = 0; e4 < 4; ++e4) {
            float t = fmaf(zz[e4], 64.0f, 1024.0f);
            int b = zbin(t);
            u32 m = fix32(elq(t, b));
            atomicAdd(&sHist[b], (u64)m);
        }
    }
    __syncthreads();

    // ---- b_ref = highest non-empty bin ----
#pragma unroll
    for (int k = 0; k < 4; ++k) {
        int s = tid + k * NTHR;
        if (sHist[s] != 0ULL) atomicMax(&sBref, s);
    }
    __syncthreads();
    const int bref = sBref;

    // ---- convert to f64 scaled values in place + build sTab ----
#pragma unroll
    for (int k = 0; k < 4; ++k) {
        int s = tid + k * NTHR;
        double sc = exp((double)(s - bref) * 0.015625);
        sTab[s] = (float)sc;
        u64 H = sHist[s];
        sD[s] = (double)H * sc;
    }
    __syncthreads();

    // ---- f64 inclusive suffix scan over 2048 bins (low-barrier: regs + shuffles) ----
    // thread t owns 4 contiguous bins [4t, 4t+3]
    {
        const int base = tid * 4;
        double b0 = sD[base + 0], b1 = sD[base + 1], b2 = sD[base + 2], b3 = sD[base + 3];
        double l3 = b3, l2 = b2 + l3, l1 = b1 + l2, l0 = b0 + l1;   // local suffixes
        const double pt = l0;                                        // thread partial
        // inclusive suffix scan of pt across the wave (guarded shfl_down)
        double ws = pt;
#pragma unroll
        for (int off = 1; off < 64; off <<= 1) {
            double o = __shfl_down(ws, off, 64);
            if (lane + off < 64) ws += o;
        }
        // exclusive (threads strictly after me, within wave)
        double ex = __shfl_down(ws, 1, 64);
        double exw = (lane < 63) ? ex : 0.0;
        if (lane == 0) sRedD[tid >> 6] = ws;   // wave total
        __syncthreads();
        double woff = 0.0;
        {
            int w = tid >> 6;
            for (int w2 = w + 1; w2 < NWAVES; ++w2) woff += sRedD[w2];
        }
        double excl = exw + woff;              // sum over bins >= 4(t+1)
        sD[base + 0] = l0 + excl;
        sD[base + 1] = l1 + excl;
        sD[base + 2] = l2 + excl;
        sD[base + 3] = l3 + excl;
        __syncthreads();
    }
    const double T = 0.9 * sD[0];

    // ---- crossing detection ----
#pragma unroll
    for (int k = 0; k < 4; ++k) {
        int s = tid + k * NTHR;
        double Ai = sD[s];
        double As = (s + 1 < NBINS2) ? sD[s + 1] : 0.0;
        bool dropped = (As >= T);
        bool keptf = (Ai <= T);
        if (dropped) atomicMax(&sMaxDrop, s);
        if (!dropped && !keptf) { sB = s; sCross = 1; }
    }
    __syncthreads();
    if (tid == 0) {
        int B = sCross ? sB : sMaxDrop;
        sB = B;
        double As = (B + 1 < NBINS2) ? sD[B + 1] : 0.0;
        if (B < 0) As = sD[0];
        sAsD = As;
        sSfpD = As;
        sScaleB = (B >= 0) ? exp((double)(B - bref) * 0.015625) : 1.0;
    }
    __syncthreads();

    const int Bst = sB;
    const int cross = sCross;
    const double AsD = sAsD;
    const double dScaleB = sScaleB;

    // ---- P2: exact in-bin resolution (bin-local integer masses) ----
    if (cross) {
        for (int v4 = tid; v4 < NV4; v4 += NTHR) {
            float4 f = lrow4[v4];
            if (v4 == (MASKID >> 2)) f.w = -1000000.0f;
            float zz[4] = {f.x, f.y, f.z, f.w};
#pragma unroll
            for (int e4 = 0; e4 < 4; ++e4) {
                float t = fmaf(zz[e4], 64.0f, 1024.0f);
                int b = zbin(t);
                if (b == Bst) {
                    u32 m = fix32(elq(t, b));
                    int pos = atomicAdd(&sCnt, 1);
                    if (pos < LISTCAP) sList[pos] = m;
                }
            }
        }
        __syncthreads();
        const int K = sCnt < LISTCAP ? sCnt : LISTCAP;
        for (int jj = tid; jj < K; jj += NTHR) {
            u32 mj = sList[jj];
            u64 isum = 0ULL;
            for (int q2 = 0; q2 < K; ++q2) {
                u32 mv = sList[q2];
                if (mv >= mj) isum += (u64)mv;
            }
            double s = AsD + (double)isum * dScaleB;
            if (s <= T) atomicMin(&sTau, mj);
        }
        __syncthreads();
        u32 tl = sTau;
        if (tl != 0xFFFFFFFFu) {
            u64 part = 0ULL;
            for (int q2 = tid; q2 < K; q2 += NTHR) {
                u32 mv = sList[q2];
                if (mv >= tl) part += (u64)mv;
            }
            if (part) atomicAdd(&sPart, part);
        }
        __syncthreads();
        if (tid == 0 && tl != 0xFFFFFFFFu)
            sSfpD = AsD + (double)sPart * dScaleB;
        __syncthreads();
    }

    const u32 tauU = (cross && sTau != 0xFFFFFFFFu) ? sTau : 0xFFFFFFFFu;
    const float invSf = (float)(4294967296.0 / sSfpD);

    // rescale sTab by invS so P3's p is a single multiply
#pragma unroll
    for (int k = 0; k < 4; ++k) sTab[tid + k * NTHR] *= invSf;

    // mask_prob in f64, replicating the reference expression order
    double mpd, omd;
    {
        double td = (double)sTT;
        mpd = ((1.0 - 1e-3) * (td - 0.05)) / ((1.0 - 1e-3) * td);
        omd = 1.0 - mpd;
    }
    const float mqf = (float)(mpd / omd);   // mask candidate in om-scaled units
    __syncthreads();

    // ---- P3: write p_x0, screen r' = p/g (om dropped: order-preserving),
    //              track top-2 (r', p, i) per thread ----
    float r1 = -3.0e38f, r2 = -3.0e38f;
    float q1 = 0.0f,     q2 = 0.0f;
    int   i1 = 0,        i2 = 0;
    for (int v4 = tid; v4 < NV4; v4 += NTHR) {
        float4 uf = urow4[v4];
        float4 f = lrow4[v4];
        if (v4 == (MASKID >> 2)) f.w = -1000000.0f;
        float zz[4] = {f.x, f.y, f.z, f.w};
        float uu[4] = {uf.x, uf.y, uf.z, uf.w};
        float pp[4];
        const int i0 = v4 * 4;
#pragma unroll
        for (int e4 = 0; e4 < 4; ++e4) {
            float t = fmaf(zz[e4], 64.0f, 1024.0f);
            int b = zbin(t);
            float el = elq(t, b);
            bool kept = (b > Bst) || (b == Bst && fix32(el) >= tauU);
            float p = kept ? el * sTab[b] : 0.0f;
            pp[e4] = p;
            float g = -__logf(1e-10f - __logf(uu[e4] + 1e-10f));
            float r = p * __builtin_amdgcn_rcpf(g + 1e-10f);
            if (r > r1)      { r2 = r1; q2 = q1; i2 = i1; r1 = r; q1 = p; i1 = i0 + e4; }
            else if (r > r2) { r2 = r;  q2 = p;  i2 = i0 + e4; }
        }
        float4 po;
        po.x = pp[0]; po.y = pp[1]; po.z = pp[2]; po.w = pp[3];
        ((float4*)prow)[v4] = po;
    }
    // inject the MASK candidate (om-scaled q = mp/om)
    if (tid == ((MASKID >> 2) % NTHR)) {
        float um = urowf[MASKID];
        float g = -__logf(1e-10f - __logf(um + 1e-10f));
        float rm = mqf * __builtin_amdgcn_rcpf(g + 1e-10f);
        if (rm > r1)      { r2 = r1; q2 = q1; i2 = i1; r1 = rm; q1 = 0.0f; i1 = MASKID; }
        else if (rm > r2) { r2 = rm; q2 = 0.0f; i2 = MASKID; }
    }

    // ---- refine the 2 candidates: exact f64 ratio (g is the critical part) ----
    double best; int bidx;
    {
        double qa = (i1 == MASKID) ? mpd : (double)q1 * omd;
        double g1 = -log(-log((double)urowf[i1] + 1e-10) + 1e-10);
        best = qa / (g1 + 1e-10);
        bidx = i1;
        double qb = (i2 == MASKID) ? mpd : (double)q2 * omd;
        double g2 = -log(-log((double)urowf[i2] + 1e-10) + 1e-10);
        double rd = qb / (g2 + 1e-10);
        if (rd > best || (rd == best && i2 < bidx)) { best = rd; bidx = i2; }
    }

    for (int off = 32; off > 0; off >>= 1) {
        double ov = __shfl_down(best, off, 64);
        int oi = __shfl_down(bidx, off, 64);
        if (ov > best || (ov == best && oi < bidx)) { best = ov; bidx = oi; }
    }
    if (lane == 0) { sRedD[tid >> 6] = best; sRedI[tid >> 6] = bidx; }
    __syncthreads();
    if (tid == 0) {
        best = sRedD[0]; bidx = sRedI[0];
        for (int w = 1; w < NWAVES; ++w) {
            double ov = sRedD[w]; int oi = sRedI[w];
            if (ov > best || (ov == best && oi < bidx)) { best = ov; bidx = oi; }
        }
        int xv = xin[row];
        out[row] = (float)((xv == MASKID) ? bidx : xv);
    }
}

extern "C" void kernel_launch(void* const* d_in, const int* in_sizes, int n_in,
                              void* d_out, int out_size, void* d_ws, size_t ws_size,
                              hipStream_t stream) {
    const int* x = (const int*)d_in[0];
    const float* logits = (const float*)d_in[1];
    const float* t = (const float*)d_in[2];
    const float* u = (const float*)d_in[3];
    float* out = (float*)d_out;
    const int rows = in_sizes[0];  // B*S = 2048
    hipLaunchKernelGGL(mdlm_kernel, dim3(rows), dim3(NTHR), 0, stream,
                       x, logits, t, u, out, rows);
}